// Round 7
// baseline (866.821 us; speedup 1.0000x reference)
//
#include <hip/hip_runtime.h>

#define NROWS 65536
#define FEA   512
#define MEM   2000
#define MEMP  2048
#define LAMBDA 0.0025f
#define EPS    1e-12f

#define PLX ((long)NROWS * FEA)   // elements per x plane
#define PLW ((long)MEMP * FEA)    // elements per W plane

typedef unsigned short ushort_t;
typedef __attribute__((ext_vector_type(8))) short bf16x8;
typedef __attribute__((ext_vector_type(4))) float f32x4;

// ---------- bf16 split helpers (RNE) ----------
__device__ inline ushort_t f2bf(float f) {
  unsigned int u = __float_as_uint(f);
  unsigned int r = (u + 0x7FFFu + ((u >> 16) & 1u)) >> 16;
  return (ushort_t)r;
}
__device__ inline float bf2f(ushort_t h) {
  return __uint_as_float(((unsigned int)h) << 16);
}

__device__ inline void gload_lds16(const void* g, void* l) {
  __builtin_amdgcn_global_load_lds(
      (const __attribute__((address_space(1))) unsigned int*)g,
      (__attribute__((address_space(3))) unsigned int*)l, 16, 0, 0);
}

// ------------------------------------------------------------------
// K0a: split x (fp32) -> xh, xl bf16 planes (stored in out region)
// ------------------------------------------------------------------
__global__ __launch_bounds__(256) void split_x(const float* __restrict__ x,
                                               ushort_t* __restrict__ xpl) {
  const long n4 = PLX / 4;
  long i = (long)blockIdx.x * 256 + threadIdx.x;
  const long stride = (long)gridDim.x * 256;
  for (; i < n4; i += stride) {
    float4 v = ((const float4*)x)[i];
    float f[4] = {v.x, v.y, v.z, v.w};
    ushort_t hh[4], ll[4];
#pragma unroll
    for (int j = 0; j < 4; ++j) {
      hh[j] = f2bf(f[j]);
      ll[j] = f2bf(f[j] - bf2f(hh[j]));
    }
    ushort4 h; h.x = hh[0]; h.y = hh[1]; h.z = hh[2]; h.w = hh[3];
    ushort4 l; l.x = ll[0]; l.y = ll[1]; l.z = ll[2]; l.w = ll[3];
    ((ushort4*)xpl)[i] = h;
    ((ushort4*)(xpl + PLX))[i] = l;
  }
}

// ------------------------------------------------------------------
// K0b: split W -> wh, wl planes, padded to 2048 rows (zeros)
// ------------------------------------------------------------------
__global__ __launch_bounds__(256) void split_w(const float* __restrict__ W,
                                               ushort_t* __restrict__ wpl) {
  long i = (long)blockIdx.x * 256 + threadIdx.x;
  if (i >= PLW / 4) return;
  long row = i / (FEA / 4);
  ushort4 h = {0, 0, 0, 0}, l = {0, 0, 0, 0};
  if (row < MEM) {
    float4 v = ((const float4*)W)[i];
    float f[4] = {v.x, v.y, v.z, v.w};
    ushort_t hh[4], ll[4];
#pragma unroll
    for (int j = 0; j < 4; ++j) {
      hh[j] = f2bf(f[j]);
      ll[j] = f2bf(f[j] - bf2f(hh[j]));
    }
    h.x = hh[0]; h.y = hh[1]; h.z = hh[2]; h.w = hh[3];
    l.x = ll[0]; l.y = ll[1]; l.z = ll[2]; l.w = ll[3];
  }
  ((ushort4*)wpl)[i] = h;
  ((ushort4*)(wpl + PLW))[i] = l;
}

// ------------------------------------------------------------------
// K1 (m201 faithful port, split-bf16 3-product):
// BM=BN=128, BK=64 (2 k-steps of 32), 8 waves 2Mx4N, 16x16x32 MFMA.
// LDS: A,B each [2 dbuf][2 k-half][128 rows][128 B] = 64 KB -> 128 KB.
// Row layout logical: [plane(2)][k-octet(4)] 16B slots; phys slot =
// logical ^ (row&7), applied on stage SOURCE and ds_read (rule #21).
// Phase = {k-step, m-half}: reads + 1 stage-unit + bar + lgkm0 + 12
// MFMA + [vmcnt(8)] + bar. Sub-slot sliding window: p2/p3 of tile t
// stage s0(t+2) into tile-t's just-consumed s0 space.
// ------------------------------------------------------------------
__device__ __forceinline__ void stage_unit(const ushort_t* __restrict__ pl0,
                                           long planeStride, long row0,
                                           int j, int s, int tid,
                                           ushort_t* dstBase) {
  ushort_t* dst = dstBase + (size_t)(j & 1) * 16384 + (size_t)s * 8192;
#pragma unroll
  for (int i = 0; i < 2; ++i) {
    int id = i * 512 + tid;       // 0..1023 positions of 16 B
    int row = id >> 3;            // 0..127
    int ps = id & 7;              // physical 16B slot
    int ls = ps ^ (row & 7);      // logical slot (XOR involution)
    int pl = ls >> 2, kc = ls & 3;
    long goff = (long)pl * planeStride + (row0 + row) * FEA + j * 64 + s * 32 + kc * 8;
    gload_lds16(pl0 + goff, dst + (size_t)id * 8);
  }
}

// PAR: 0 = steady, 1 = tile KT-2 (no s0(t+2) stage), 2 = last tile
template <int PAR>
__device__ __forceinline__ void ktile(
    int t, int tid, int l15, int lq, int wm, int wn,
    const ushort_t* __restrict__ xpl, const ushort_t* __restrict__ wpl,
    long rm0, long cn0, ushort_t* ldsA, ushort_t* ldsB, f32x4 (&acc)[4][2]) {
  const ushort_t* Ab = ldsA + (size_t)(t & 1) * 16384;
  const ushort_t* Bb = ldsB + (size_t)(t & 1) * 16384;

  bf16x8 a[2][2], b[2][2];

  auto readA = [&](int S, int MH) {
#pragma unroll
    for (int mf = 0; mf < 2; ++mf) {
      int r = wm * 64 + MH * 32 + mf * 16 + l15;
      int rx = r & 7;
#pragma unroll
      for (int pl = 0; pl < 2; ++pl)
        a[mf][pl] = *(const bf16x8*)(Ab + (size_t)S * 8192 + r * 64 +
                                     ((((pl << 2) + lq) ^ rx) * 8));
    }
  };
  auto readB = [&](int S) {
#pragma unroll
    for (int nf = 0; nf < 2; ++nf) {
      int r = wn * 32 + nf * 16 + l15;
      int rx = r & 7;
#pragma unroll
      for (int pl = 0; pl < 2; ++pl)
        b[nf][pl] = *(const bf16x8*)(Bb + (size_t)S * 8192 + r * 64 +
                                     ((((pl << 2) + lq) ^ rx) * 8));
    }
  };
  auto mfma12 = [&](int MH) {
    __builtin_amdgcn_s_setprio(1);
#pragma unroll
    for (int mf = 0; mf < 2; ++mf)
#pragma unroll
      for (int nf = 0; nf < 2; ++nf)
        acc[MH * 2 + mf][nf] = __builtin_amdgcn_mfma_f32_16x16x32_bf16(
            a[mf][0], b[nf][0], acc[MH * 2 + mf][nf], 0, 0, 0);
#pragma unroll
    for (int mf = 0; mf < 2; ++mf)
#pragma unroll
      for (int nf = 0; nf < 2; ++nf)
        acc[MH * 2 + mf][nf] = __builtin_amdgcn_mfma_f32_16x16x32_bf16(
            a[mf][0], b[nf][1], acc[MH * 2 + mf][nf], 0, 0, 0);
#pragma unroll
    for (int mf = 0; mf < 2; ++mf)
#pragma unroll
      for (int nf = 0; nf < 2; ++nf)
        acc[MH * 2 + mf][nf] = __builtin_amdgcn_mfma_f32_16x16x32_bf16(
            a[mf][1], b[nf][0], acc[MH * 2 + mf][nf], 0, 0, 0);
    __builtin_amdgcn_s_setprio(0);
  };

  // ---- phase 0: (s0, mh0); stage A-s1(t+1) ----
  readA(0, 0); readB(0);
  if (PAR < 2) stage_unit(xpl, PLX, rm0, t + 1, 1, tid, ldsA);
  asm volatile("s_barrier" ::: "memory");
  asm volatile("s_waitcnt lgkmcnt(0)" ::: "memory");
  __builtin_amdgcn_sched_barrier(0);
  mfma12(0);
  asm volatile("s_barrier" ::: "memory");

  // ---- phase 1: (s0, mh1); stage B-s1(t+1); vmcnt ----
  readA(0, 1);
  if (PAR < 2) stage_unit(wpl, PLW, cn0, t + 1, 1, tid, ldsB);
  asm volatile("s_barrier" ::: "memory");
  asm volatile("s_waitcnt lgkmcnt(0)" ::: "memory");
  __builtin_amdgcn_sched_barrier(0);
  mfma12(1);
  if (PAR < 2) asm volatile("s_waitcnt vmcnt(8)" ::: "memory");
  else         asm volatile("s_waitcnt vmcnt(0)" ::: "memory");
  asm volatile("s_barrier" ::: "memory");

  // ---- phase 2: (s1, mh0); stage A-s0(t+2) into just-freed space ----
  readA(1, 0); readB(1);
  if (PAR == 0) stage_unit(xpl, PLX, rm0, t + 2, 0, tid, ldsA);
  asm volatile("s_barrier" ::: "memory");
  asm volatile("s_waitcnt lgkmcnt(0)" ::: "memory");
  __builtin_amdgcn_sched_barrier(0);
  mfma12(0);
  asm volatile("s_barrier" ::: "memory");

  // ---- phase 3: (s1, mh1); stage B-s0(t+2); vmcnt ----
  readA(1, 1);
  if (PAR == 0) stage_unit(wpl, PLW, cn0, t + 2, 0, tid, ldsB);
  asm volatile("s_barrier" ::: "memory");
  asm volatile("s_waitcnt lgkmcnt(0)" ::: "memory");
  __builtin_amdgcn_sched_barrier(0);
  mfma12(1);
  if (PAR == 0) {
    asm volatile("s_waitcnt vmcnt(8)" ::: "memory");
    asm volatile("s_barrier" ::: "memory");
  } else if (PAR == 1) {
    asm volatile("s_waitcnt vmcnt(4)" ::: "memory");
    asm volatile("s_barrier" ::: "memory");
  }
  // PAR==2: kernel ends; no wait needed
}

__global__ __launch_bounds__(512, 2) void gemm_mfma5(
    const ushort_t* __restrict__ xpl, const ushort_t* __restrict__ wpl,
    float* __restrict__ S) {
  __shared__ alignas(16) ushort_t lds[65536];  // A 64 KB | B 64 KB
  ushort_t* ldsA = lds;
  ushort_t* ldsB = lds + 32768;

  const int tid = threadIdx.x;
  const int wid = tid >> 6, lane = tid & 63;
  const int l15 = lane & 15, lq = lane >> 4;   // lq 0..3
  const int wm = wid >> 2, wn = wid & 3;       // 2M x 4N waves

  // XCD-chunked bijective swizzle: 8192 wgs = 8 xcd x 64 mt x 16 nt
  int wg = blockIdx.x;
  int xcd = wg & 7, idx = wg >> 3;             // idx 0..1023
  const int mt = xcd * 64 + (idx >> 4);
  const int nt = idx & 15;
  const long rm0 = (long)mt * 128;
  const long cn0 = (long)nt * 128;

  f32x4 acc[4][2] = {};

  // prologue: units in steady-state FIFO order; vmcnt(8) retires s0(0)
  stage_unit(xpl, PLX, rm0, 0, 0, tid, ldsA);
  stage_unit(wpl, PLW, cn0, 0, 0, tid, ldsB);
  stage_unit(xpl, PLX, rm0, 0, 1, tid, ldsA);
  stage_unit(wpl, PLW, cn0, 0, 1, tid, ldsB);
  stage_unit(xpl, PLX, rm0, 1, 0, tid, ldsA);
  stage_unit(wpl, PLW, cn0, 1, 0, tid, ldsB);
  asm volatile("s_waitcnt vmcnt(8)" ::: "memory");
  asm volatile("s_barrier" ::: "memory");

  // 8 K-tiles of BK=64
  for (int t = 0; t < 6; ++t)
    ktile<0>(t, tid, l15, lq, wm, wn, xpl, wpl, rm0, cn0, ldsA, ldsB, acc);
  ktile<1>(6, tid, l15, lq, wm, wn, xpl, wpl, rm0, cn0, ldsA, ldsB, acc);
  ktile<2>(7, tid, l15, lq, wm, wn, xpl, wpl, rm0, cn0, ldsA, ldsB, acc);

  // epilogue: 16x16 C/D layout col=lane&15, row=(lane>>4)*4+reg
#pragma unroll
  for (int mf = 0; mf < 4; ++mf)
#pragma unroll
    for (int nf = 0; nf < 2; ++nf) {
      int col = (int)cn0 + wn * 32 + nf * 16 + l15;
      if (col < MEM) {
        long rbase = rm0 + wm * 64 + mf * 16 + lq * 4;
#pragma unroll
        for (int r = 0; r < 4; ++r)
          S[(rbase + r) * MEM + col] = acc[mf][nf][r];
      }
    }
}

// ------------------------------------------------------------------
// Fallback fp32 GEMM (used only if ws too small)
// ------------------------------------------------------------------
#define BKF 32
__global__ __launch_bounds__(256) void gemm_scores(
    const float* __restrict__ x, const float* __restrict__ Wt,
    float* __restrict__ S) {
  __shared__ float xs[BKF][129];
  __shared__ float ws[BKF][129];
  const int tid = threadIdx.x;
  const int rm0 = blockIdx.x * 128;
  const int cn0 = blockIdx.y * 128;
  const int tx = tid & 15, ty = tid >> 4;
  const int sr = tid >> 3, kq = tid & 7;
  float acc[8][8];
#pragma unroll
  for (int i = 0; i < 8; ++i)
#pragma unroll
    for (int j = 0; j < 8; ++j) acc[i][j] = 0.f;
  for (int k0 = 0; k0 < FEA; k0 += BKF) {
#pragma unroll
    for (int b = 0; b < 4; ++b) {
      const int row = sr + 32 * b;
      float4 v = *(const float4*)(x + (size_t)(rm0 + row) * FEA + k0 + kq * 4);
      xs[kq * 4 + 0][row] = v.x; xs[kq * 4 + 1][row] = v.y;
      xs[kq * 4 + 2][row] = v.z; xs[kq * 4 + 3][row] = v.w;
      int wr = cn0 + row; wr = (wr < MEM) ? wr : (MEM - 1);
      float4 u = *(const float4*)(Wt + (size_t)wr * FEA + k0 + kq * 4);
      ws[kq * 4 + 0][row] = u.x; ws[kq * 4 + 1][row] = u.y;
      ws[kq * 4 + 2][row] = u.z; ws[kq * 4 + 3][row] = u.w;
    }
    __syncthreads();
#pragma unroll 8
    for (int k = 0; k < BKF; ++k) {
      float a[8], bb[8];
      float4 t0 = *(const float4*)&xs[k][4 * ty];
      float4 t1 = *(const float4*)&xs[k][64 + 4 * ty];
      a[0] = t0.x; a[1] = t0.y; a[2] = t0.z; a[3] = t0.w;
      a[4] = t1.x; a[5] = t1.y; a[6] = t1.z; a[7] = t1.w;
      float4 u0 = *(const float4*)&ws[k][4 * tx];
      float4 u1 = *(const float4*)&ws[k][64 + 4 * tx];
      bb[0] = u0.x; bb[1] = u0.y; bb[2] = u0.z; bb[3] = u0.w;
      bb[4] = u1.x; bb[5] = u1.y; bb[6] = u1.z; bb[7] = u1.w;
#pragma unroll
      for (int i = 0; i < 8; ++i)
#pragma unroll
        for (int j = 0; j < 8; ++j)
          acc[i][j] = fmaf(a[i], bb[j], acc[i][j]);
    }
    __syncthreads();
  }
#pragma unroll
  for (int i = 0; i < 8; ++i) {
    const int row = rm0 + ((i < 4) ? (4 * ty + i) : (64 + 4 * ty + (i - 4)));
    const int c0 = cn0 + 4 * tx;
    const int c1 = cn0 + 64 + 4 * tx;
    if (c0 < MEM) {
      float4 v; v.x = acc[i][0]; v.y = acc[i][1]; v.z = acc[i][2]; v.w = acc[i][3];
      *(float4*)(S + (size_t)row * MEM + c0) = v;
    }
    if (c1 < MEM) {
      float4 v; v.x = acc[i][4]; v.y = acc[i][5]; v.z = acc[i][6]; v.w = acc[i][7];
      *(float4*)(S + (size_t)row * MEM + c1) = v;
    }
  }
}

// ------------------------------------------------------------------
// K2: softmax -> hard shrink -> renorm -> write att + sparse out
// ------------------------------------------------------------------
__global__ __launch_bounds__(512) void softmax_shrink_out(
    const float* __restrict__ Wt, float* __restrict__ out,
    float* __restrict__ att /* raw scores on entry */) {
  __shared__ float sl[8 * MEM];
  const int tid = threadIdx.x;
  const int r0 = blockIdx.x * 8;
  {
    const float* Sblk = att + (size_t)r0 * MEM;
#pragma unroll
    for (int jj = 0; jj < 8; ++jj) {
      int q = tid + 512 * jj;
      if (q < (8 * MEM) / 4) {
        float4 v = *(const float4*)(Sblk + 4 * q);
        *(float4*)&sl[4 * q] = v;
      }
    }
  }
  __syncthreads();
  const int w = tid >> 6;
  const int l = tid & 63;
  float* row_lds = &sl[w * MEM];
  const int grow = r0 + w;

  float m = -INFINITY;
  for (int j = 0; j < 32; ++j) {
    int c = l + 64 * j;
    if (c < MEM) m = fmaxf(m, row_lds[c]);
  }
#pragma unroll
  for (int off = 32; off; off >>= 1) m = fmaxf(m, __shfl_xor(m, off));

  float s = 0.f;
  for (int j = 0; j < 32; ++j) {
    int c = l + 64 * j;
    if (c < MEM) {
      float e = expf(row_lds[c] - m);
      row_lds[c] = e;
      s += e;
    }
  }
#pragma unroll
  for (int off = 32; off; off >>= 1) s += __shfl_xor(s, off);

  float qs = 0.f;
  for (int j = 0; j < 32; ++j) {
    int c = l + 64 * j;
    if (c < MEM) {
      float p = row_lds[c] / s;
      float d = p - LAMBDA;
      float q = fmaxf(d, 0.f) * p / (fabsf(d) + EPS);
      row_lds[c] = q;
      qs += q;
    }
  }
#pragma unroll
  for (int off = 32; off; off >>= 1) qs += __shfl_xor(qs, off);
  const float denom = fmaxf(qs, EPS);

  float4 oa0 = {0.f, 0.f, 0.f, 0.f};
  float4 oa1 = {0.f, 0.f, 0.f, 0.f};
  for (int j = 0; j < 32; ++j) {
    int c = l + 64 * j;
    float a = 0.f;
    if (c < MEM) {
      a = row_lds[c] / denom;
      att[(size_t)grow * MEM + c] = a;
    }
    unsigned long long msk = __ballot(a > 0.f);
    while (msk) {
      int b = __ffsll(msk) - 1;
      msk &= msk - 1;
      float av = __shfl(a, b);
      int cc = b + 64 * j;
      const float* wp = Wt + (size_t)cc * FEA;
      float4 w0 = *(const float4*)(wp + 4 * l);
      float4 w1 = *(const float4*)(wp + 256 + 4 * l);
      oa0.x = fmaf(av, w0.x, oa0.x); oa0.y = fmaf(av, w0.y, oa0.y);
      oa0.z = fmaf(av, w0.z, oa0.z); oa0.w = fmaf(av, w0.w, oa0.w);
      oa1.x = fmaf(av, w1.x, oa1.x); oa1.y = fmaf(av, w1.y, oa1.y);
      oa1.z = fmaf(av, w1.z, oa1.z); oa1.w = fmaf(av, w1.w, oa1.w);
    }
  }
  float* op = out + (size_t)grow * FEA;
  *(float4*)(op + 4 * l) = oa0;
  *(float4*)(op + 256 + 4 * l) = oa1;
}

// ------------------------------------------------------------------
extern "C" void kernel_launch(void* const* d_in, const int* in_sizes, int n_in,
                              void* d_out, int out_size, void* d_ws, size_t ws_size,
                              hipStream_t stream) {
  (void)in_sizes; (void)n_in; (void)out_size;
  const float* x = (const float*)d_in[0];
  const float* W = (const float*)d_in[1];
  float* out = (float*)d_out;
  float* att = (float*)d_out + (size_t)NROWS * FEA;

  const size_t w_need = (size_t)PLW * 2 * sizeof(ushort_t);  // 4 MB
  if (ws_size >= w_need) {
    ushort_t* xpl = (ushort_t*)d_out;  // out region: exactly fits 2 x-planes
    ushort_t* wpl = (ushort_t*)d_ws;
    split_x<<<2048, 256, 0, stream>>>(x, xpl);
    split_w<<<(int)(PLW / 4 / 256), 256, 0, stream>>>(W, wpl);
    gemm_mfma5<<<8192, 512, 0, stream>>>(xpl, wpl, att);
  } else {
    dim3 g1(NROWS / 128, (MEM + 127) / 128);
    gemm_scores<<<g1, 256, 0, stream>>>(x, W, att);
  }
  softmax_shrink_out<<<NROWS / 8, 512, 0, stream>>>(W, out, att);
}

// Round 8
// 760.562 us; speedup vs baseline: 1.1397x; 1.1397x over previous
//
#include <hip/hip_runtime.h>

#define NROWS 65536
#define FEA   512
#define MEM   2000
#define MEMP  2048
#define LAMBDA 0.0025f
#define EPS    1e-12f

#define PLX ((long)NROWS * FEA)   // elements per x plane
#define PLW ((long)MEMP * FEA)    // elements per W plane

typedef unsigned short ushort_t;
typedef __attribute__((ext_vector_type(8))) short bf16x8;
typedef __attribute__((ext_vector_type(16))) float f32x16;

// ---------- bf16 split helpers (RNE) ----------
__device__ inline ushort_t f2bf(float f) {
  unsigned int u = __float_as_uint(f);
  unsigned int r = (u + 0x7FFFu + ((u >> 16) & 1u)) >> 16;
  return (ushort_t)r;
}
__device__ inline float bf2f(ushort_t h) {
  return __uint_as_float(((unsigned int)h) << 16);
}

__device__ inline void gload_lds16(const void* g, void* l) {
  __builtin_amdgcn_global_load_lds(
      (const __attribute__((address_space(1))) unsigned int*)g,
      (__attribute__((address_space(3))) unsigned int*)l, 16, 0, 0);
}

// ------------------------------------------------------------------
// K0a: split x (fp32) -> xh, xl bf16 planes (stored in out region)
// ------------------------------------------------------------------
__global__ __launch_bounds__(256) void split_x(const float* __restrict__ x,
                                               ushort_t* __restrict__ xpl) {
  const long n4 = PLX / 4;
  long i = (long)blockIdx.x * 256 + threadIdx.x;
  const long stride = (long)gridDim.x * 256;
  for (; i < n4; i += stride) {
    float4 v = ((const float4*)x)[i];
    float f[4] = {v.x, v.y, v.z, v.w};
    ushort_t hh[4], ll[4];
#pragma unroll
    for (int j = 0; j < 4; ++j) {
      hh[j] = f2bf(f[j]);
      ll[j] = f2bf(f[j] - bf2f(hh[j]));
    }
    ushort4 h; h.x = hh[0]; h.y = hh[1]; h.z = hh[2]; h.w = hh[3];
    ushort4 l; l.x = ll[0]; l.y = ll[1]; l.z = ll[2]; l.w = ll[3];
    ((ushort4*)xpl)[i] = h;
    ((ushort4*)(xpl + PLX))[i] = l;
  }
}

// ------------------------------------------------------------------
// K0b: split W -> wh, wl planes, padded to 2048 rows (zeros)
// ------------------------------------------------------------------
__global__ __launch_bounds__(256) void split_w(const float* __restrict__ W,
                                               ushort_t* __restrict__ wpl) {
  long i = (long)blockIdx.x * 256 + threadIdx.x;
  if (i >= PLW / 4) return;
  long row = i / (FEA / 4);
  ushort4 h = {0, 0, 0, 0}, l = {0, 0, 0, 0};
  if (row < MEM) {
    float4 v = ((const float4*)W)[i];
    float f[4] = {v.x, v.y, v.z, v.w};
    ushort_t hh[4], ll[4];
#pragma unroll
    for (int j = 0; j < 4; ++j) {
      hh[j] = f2bf(f[j]);
      ll[j] = f2bf(f[j] - bf2f(hh[j]));
    }
    h.x = hh[0]; h.y = hh[1]; h.z = hh[2]; h.w = hh[3];
    l.x = ll[0]; l.y = ll[1]; l.z = ll[2]; l.w = ll[3];
  }
  ((ushort4*)wpl)[i] = h;
  ((ushort4*)(wpl + PLW))[i] = l;
}

// ------------------------------------------------------------------
// K1: S = x @ W^T, split-bf16 (3 products), 256x256 tile, BK=32.
// Conflict-free LDS: slot = [256 rows][128 B], row = 2 planes x 4
// k-octets of 16 B; phys chunk = c ^ (row&7)  (r7-proven geometry).
// Ring-2 (A 64 KB + B 64 KB). ONE barrier per region, no intra-region
// barrier: {stage(t+1) | reads k0 | 24 MFMA | reads k1 | 24 MFMA |
// vmcnt(0) | s_barrier} -- waves drift, MFMA covers sibling reads.
// ------------------------------------------------------------------
__device__ __forceinline__ void stageOp(const ushort_t* __restrict__ pl0,
                                        long planeStride, long row0, int t,
                                        int tid, ushort_t* dst /*slot base*/) {
#pragma unroll
  for (int i = 0; i < 4; ++i) {
    int id = i * 512 + tid;          // 0..2047 16B-positions
    int row = id >> 3;               // 0..255
    int ps = id & 7;                 // physical chunk
    int ls = ps ^ (row & 7);         // logical chunk (involution)
    int pl = ls >> 2, ko = ls & 3;
    long goff = (long)pl * planeStride + (row0 + row) * FEA + t * 32 + ko * 8;
    gload_lds16(pl0 + goff, dst + (size_t)id * 8);
  }
}

__global__ __launch_bounds__(512, 2) void gemm_mfma6(
    const ushort_t* __restrict__ xpl, const ushort_t* __restrict__ wpl,
    float* __restrict__ S) {
  __shared__ alignas(16) ushort_t lds[65536];  // A ring2 64 KB | B ring2 64 KB
  ushort_t* ldsA = lds;
  ushort_t* ldsB = lds + 32768;

  const int tid = threadIdx.x;
  const int wid = tid >> 6, lane = tid & 63;
  const int l32 = lane & 31, lh = lane >> 5;
  const int wm = wid >> 2, wn = wid & 3;   // 2M x 4N waves

  // XCD-chunked bijective swizzle (2048 wgs): proven 197 MB fetch
  int wg = blockIdx.x;
  int xcd = wg & 7, idx = wg >> 3;
  const int mt = xcd * 32 + (idx >> 3);
  const int nt = idx & 7;
  const long rm0 = (long)mt * 256;
  const long cn0 = (long)nt * 256;

  f32x16 acc[4][2] = {};

  // prologue: stage K-tile 0 into slot 0
  stageOp(xpl, PLX, rm0, 0, tid, ldsA);
  stageOp(wpl, PLW, cn0, 0, tid, ldsB);
  asm volatile("s_waitcnt vmcnt(0)" ::: "memory");
  asm volatile("s_barrier" ::: "memory");

  for (int t = 0; t < 16; ++t) {
    const ushort_t* Ab = ldsA + (size_t)(t & 1) * 16384;
    const ushort_t* Bb = ldsB + (size_t)(t & 1) * 16384;

    if (t < 15) {  // stage next tile into the other slot (no WAR: disjoint)
      stageOp(xpl, PLX, rm0, t + 1, tid, ldsA + (size_t)((t + 1) & 1) * 16384);
      stageOp(wpl, PLW, cn0, t + 1, tid, ldsB + (size_t)((t + 1) & 1) * 16384);
    }

#pragma unroll
    for (int s = 0; s < 2; ++s) {  // two K=16 steps
      bf16x8 a[4][2], b[2][2];
#pragma unroll
      for (int mf = 0; mf < 4; ++mf) {
        int row = wm * 128 + mf * 32 + l32;
        int rx = row & 7;
        a[mf][0] = *(const bf16x8*)(Ab + row * 64 + (((s * 2 + lh) ^ rx) * 8));
        a[mf][1] = *(const bf16x8*)(Ab + row * 64 + (((4 + s * 2 + lh) ^ rx) * 8));
      }
#pragma unroll
      for (int nf = 0; nf < 2; ++nf) {
        int row = wn * 64 + nf * 32 + l32;
        int rx = row & 7;
        b[nf][0] = *(const bf16x8*)(Bb + row * 64 + (((s * 2 + lh) ^ rx) * 8));
        b[nf][1] = *(const bf16x8*)(Bb + row * 64 + (((4 + s * 2 + lh) ^ rx) * 8));
      }
      __builtin_amdgcn_s_setprio(1);
#pragma unroll
      for (int mf = 0; mf < 4; ++mf)
#pragma unroll
        for (int nf = 0; nf < 2; ++nf) {
          acc[mf][nf] = __builtin_amdgcn_mfma_f32_32x32x16_bf16(a[mf][0], b[nf][0], acc[mf][nf], 0, 0, 0);
          acc[mf][nf] = __builtin_amdgcn_mfma_f32_32x32x16_bf16(a[mf][0], b[nf][1], acc[mf][nf], 0, 0, 0);
          acc[mf][nf] = __builtin_amdgcn_mfma_f32_32x32x16_bf16(a[mf][1], b[nf][0], acc[mf][nf], 0, 0, 0);
        }
      __builtin_amdgcn_s_setprio(0);
    }

    if (t < 15) {
      asm volatile("s_waitcnt vmcnt(0)" ::: "memory");
      asm volatile("s_barrier" ::: "memory");
    }
  }

  // epilogue: C/D layout col=lane&31, row=(reg&3)+8*(reg>>2)+4*(lane>>5)
#pragma unroll
  for (int mf = 0; mf < 4; ++mf)
#pragma unroll
    for (int nf = 0; nf < 2; ++nf) {
      int col = (int)cn0 + wn * 64 + nf * 32 + l32;
      if (col < MEM) {
        long rbase = rm0 + wm * 128 + mf * 32 + 4 * lh;
#pragma unroll
        for (int r = 0; r < 16; ++r) {
          long row = rbase + (r & 3) + 8 * (r >> 2);
          S[row * MEM + col] = acc[mf][nf][r];
        }
      }
    }
}

// ------------------------------------------------------------------
// Fallback fp32 GEMM (used only if ws too small)
// ------------------------------------------------------------------
#define BKF 32
__global__ __launch_bounds__(256) void gemm_scores(
    const float* __restrict__ x, const float* __restrict__ Wt,
    float* __restrict__ S) {
  __shared__ float xs[BKF][129];
  __shared__ float ws[BKF][129];
  const int tid = threadIdx.x;
  const int rm0 = blockIdx.x * 128;
  const int cn0 = blockIdx.y * 128;
  const int tx = tid & 15, ty = tid >> 4;
  const int sr = tid >> 3, kq = tid & 7;
  float acc[8][8];
#pragma unroll
  for (int i = 0; i < 8; ++i)
#pragma unroll
    for (int j = 0; j < 8; ++j) acc[i][j] = 0.f;
  for (int k0 = 0; k0 < FEA; k0 += BKF) {
#pragma unroll
    for (int b = 0; b < 4; ++b) {
      const int row = sr + 32 * b;
      float4 v = *(const float4*)(x + (size_t)(rm0 + row) * FEA + k0 + kq * 4);
      xs[kq * 4 + 0][row] = v.x; xs[kq * 4 + 1][row] = v.y;
      xs[kq * 4 + 2][row] = v.z; xs[kq * 4 + 3][row] = v.w;
      int wr = cn0 + row; wr = (wr < MEM) ? wr : (MEM - 1);
      float4 u = *(const float4*)(Wt + (size_t)wr * FEA + k0 + kq * 4);
      ws[kq * 4 + 0][row] = u.x; ws[kq * 4 + 1][row] = u.y;
      ws[kq * 4 + 2][row] = u.z; ws[kq * 4 + 3][row] = u.w;
    }
    __syncthreads();
#pragma unroll 8
    for (int k = 0; k < BKF; ++k) {
      float a[8], bb[8];
      float4 t0 = *(const float4*)&xs[k][4 * ty];
      float4 t1 = *(const float4*)&xs[k][64 + 4 * ty];
      a[0] = t0.x; a[1] = t0.y; a[2] = t0.z; a[3] = t0.w;
      a[4] = t1.x; a[5] = t1.y; a[6] = t1.z; a[7] = t1.w;
      float4 u0 = *(const float4*)&ws[k][4 * tx];
      float4 u1 = *(const float4*)&ws[k][64 + 4 * tx];
      bb[0] = u0.x; bb[1] = u0.y; bb[2] = u0.z; bb[3] = u0.w;
      bb[4] = u1.x; bb[5] = u1.y; bb[6] = u1.z; bb[7] = u1.w;
#pragma unroll
      for (int i = 0; i < 8; ++i)
#pragma unroll
        for (int j = 0; j < 8; ++j)
          acc[i][j] = fmaf(a[i], bb[j], acc[i][j]);
    }
    __syncthreads();
  }
#pragma unroll
  for (int i = 0; i < 8; ++i) {
    const int row = rm0 + ((i < 4) ? (4 * ty + i) : (64 + 4 * ty + (i - 4)));
    const int c0 = cn0 + 4 * tx;
    const int c1 = cn0 + 64 + 4 * tx;
    if (c0 < MEM) {
      float4 v; v.x = acc[i][0]; v.y = acc[i][1]; v.z = acc[i][2]; v.w = acc[i][3];
      *(float4*)(S + (size_t)row * MEM + c0) = v;
    }
    if (c1 < MEM) {
      float4 v; v.x = acc[i][4]; v.y = acc[i][5]; v.z = acc[i][6]; v.w = acc[i][7];
      *(float4*)(S + (size_t)row * MEM + c1) = v;
    }
  }
}

// ------------------------------------------------------------------
// K2: softmax -> hard shrink -> renorm -> write att + sparse out
// ------------------------------------------------------------------
__global__ __launch_bounds__(512) void softmax_shrink_out(
    const float* __restrict__ Wt, float* __restrict__ out,
    float* __restrict__ att /* raw scores on entry */) {
  __shared__ float sl[8 * MEM];
  const int tid = threadIdx.x;
  const int r0 = blockIdx.x * 8;
  {
    const float* Sblk = att + (size_t)r0 * MEM;
#pragma unroll
    for (int jj = 0; jj < 8; ++jj) {
      int q = tid + 512 * jj;
      if (q < (8 * MEM) / 4) {
        float4 v = *(const float4*)(Sblk + 4 * q);
        *(float4*)&sl[4 * q] = v;
      }
    }
  }
  __syncthreads();
  const int w = tid >> 6;
  const int l = tid & 63;
  float* row_lds = &sl[w * MEM];
  const int grow = r0 + w;

  float m = -INFINITY;
  for (int j = 0; j < 32; ++j) {
    int c = l + 64 * j;
    if (c < MEM) m = fmaxf(m, row_lds[c]);
  }
#pragma unroll
  for (int off = 32; off; off >>= 1) m = fmaxf(m, __shfl_xor(m, off));

  float s = 0.f;
  for (int j = 0; j < 32; ++j) {
    int c = l + 64 * j;
    if (c < MEM) {
      float e = expf(row_lds[c] - m);
      row_lds[c] = e;
      s += e;
    }
  }
#pragma unroll
  for (int off = 32; off; off >>= 1) s += __shfl_xor(s, off);

  float qs = 0.f;
  for (int j = 0; j < 32; ++j) {
    int c = l + 64 * j;
    if (c < MEM) {
      float p = row_lds[c] / s;
      float d = p - LAMBDA;
      float q = fmaxf(d, 0.f) * p / (fabsf(d) + EPS);
      row_lds[c] = q;
      qs += q;
    }
  }
#pragma unroll
  for (int off = 32; off; off >>= 1) qs += __shfl_xor(qs, off);
  const float denom = fmaxf(qs, EPS);

  float4 oa0 = {0.f, 0.f, 0.f, 0.f};
  float4 oa1 = {0.f, 0.f, 0.f, 0.f};
  for (int j = 0; j < 32; ++j) {
    int c = l + 64 * j;
    float a = 0.f;
    if (c < MEM) {
      a = row_lds[c] / denom;
      att[(size_t)grow * MEM + c] = a;
    }
    unsigned long long msk = __ballot(a > 0.f);
    while (msk) {
      int b = __ffsll(msk) - 1;
      msk &= msk - 1;
      float av = __shfl(a, b);
      int cc = b + 64 * j;
      const float* wp = Wt + (size_t)cc * FEA;
      float4 w0 = *(const float4*)(wp + 4 * l);
      float4 w1 = *(const float4*)(wp + 256 + 4 * l);
      oa0.x = fmaf(av, w0.x, oa0.x); oa0.y = fmaf(av, w0.y, oa0.y);
      oa0.z = fmaf(av, w0.z, oa0.z); oa0.w = fmaf(av, w0.w, oa0.w);
      oa1.x = fmaf(av, w1.x, oa1.x); oa1.y = fmaf(av, w1.y, oa1.y);
      oa1.z = fmaf(av, w1.z, oa1.z); oa1.w = fmaf(av, w1.w, oa1.w);
    }
  }
  float* op = out + (size_t)grow * FEA;
  *(float4*)(op + 4 * l) = oa0;
  *(float4*)(op + 256 + 4 * l) = oa1;
}

// ------------------------------------------------------------------
extern "C" void kernel_launch(void* const* d_in, const int* in_sizes, int n_in,
                              void* d_out, int out_size, void* d_ws, size_t ws_size,
                              hipStream_t stream) {
  (void)in_sizes; (void)n_in; (void)out_size;
  const float* x = (const float*)d_in[0];
  const float* W = (const float*)d_in[1];
  float* out = (float*)d_out;
  float* att = (float*)d_out + (size_t)NROWS * FEA;

  const size_t w_need = (size_t)PLW * 2 * sizeof(ushort_t);  // 4 MB
  if (ws_size >= w_need) {
    ushort_t* xpl = (ushort_t*)d_out;  // out region: exactly fits 2 x-planes
    ushort_t* wpl = (ushort_t*)d_ws;
    split_x<<<2048, 256, 0, stream>>>(x, xpl);
    split_w<<<(int)(PLW / 4 / 256), 256, 0, stream>>>(W, wpl);
    gemm_mfma6<<<2048, 512, 0, stream>>>(xpl, wpl, att);
  } else {
    dim3 g1(NROWS / 128, (MEM + 127) / 128);
    gemm_scores<<<g1, 256, 0, stream>>>(x, W, att);
  }
  softmax_shrink_out<<<NROWS / 8, 512, 0, stream>>>(W, out, att);
}

// Round 9
// 722.357 us; speedup vs baseline: 1.2000x; 1.0529x over previous
//
#include <hip/hip_runtime.h>

#define NROWS 65536
#define FEA   512
#define MEM   2000
#define MEMP  2048
#define LAMBDA 0.0025f
#define EPS    1e-12f

#define PLX ((long)NROWS * FEA)   // elements per x plane
#define PLW ((long)MEMP * FEA)    // elements per W plane

typedef unsigned short ushort_t;
typedef __attribute__((ext_vector_type(8))) short bf16x8;
typedef __attribute__((ext_vector_type(4))) float f32x4;

// ---------- bf16 split helpers (RNE) ----------
__device__ inline ushort_t f2bf(float f) {
  unsigned int u = __float_as_uint(f);
  unsigned int r = (u + 0x7FFFu + ((u >> 16) & 1u)) >> 16;
  return (ushort_t)r;
}
__device__ inline float bf2f(ushort_t h) {
  return __uint_as_float(((unsigned int)h) << 16);
}

__device__ inline void gload_lds16(const void* g, void* l) {
  __builtin_amdgcn_global_load_lds(
      (const __attribute__((address_space(1))) unsigned int*)g,
      (__attribute__((address_space(3))) unsigned int*)l, 16, 0, 0);
}

// ------------------------------------------------------------------
// K0a: split x (fp32) -> xh, xl bf16 planes (stored in out region)
// ------------------------------------------------------------------
__global__ __launch_bounds__(256) void split_x(const float* __restrict__ x,
                                               ushort_t* __restrict__ xpl) {
  const long n4 = PLX / 4;
  long i = (long)blockIdx.x * 256 + threadIdx.x;
  const long stride = (long)gridDim.x * 256;
  for (; i < n4; i += stride) {
    float4 v = ((const float4*)x)[i];
    float f[4] = {v.x, v.y, v.z, v.w};
    ushort_t hh[4], ll[4];
#pragma unroll
    for (int j = 0; j < 4; ++j) {
      hh[j] = f2bf(f[j]);
      ll[j] = f2bf(f[j] - bf2f(hh[j]));
    }
    ushort4 h; h.x = hh[0]; h.y = hh[1]; h.z = hh[2]; h.w = hh[3];
    ushort4 l; l.x = ll[0]; l.y = ll[1]; l.z = ll[2]; l.w = ll[3];
    ((ushort4*)xpl)[i] = h;
    ((ushort4*)(xpl + PLX))[i] = l;
  }
}

// ------------------------------------------------------------------
// K0b: split W -> wh, wl planes, padded to 2048 rows (zeros)
// ------------------------------------------------------------------
__global__ __launch_bounds__(256) void split_w(const float* __restrict__ W,
                                               ushort_t* __restrict__ wpl) {
  long i = (long)blockIdx.x * 256 + threadIdx.x;
  if (i >= PLW / 4) return;
  long row = i / (FEA / 4);
  ushort4 h = {0, 0, 0, 0}, l = {0, 0, 0, 0};
  if (row < MEM) {
    float4 v = ((const float4*)W)[i];
    float f[4] = {v.x, v.y, v.z, v.w};
    ushort_t hh[4], ll[4];
#pragma unroll
    for (int j = 0; j < 4; ++j) {
      hh[j] = f2bf(f[j]);
      ll[j] = f2bf(f[j] - bf2f(hh[j]));
    }
    h.x = hh[0]; h.y = hh[1]; h.z = hh[2]; h.w = hh[3];
    l.x = ll[0]; l.y = ll[1]; l.z = ll[2]; l.w = ll[3];
  }
  ((ushort4*)wpl)[i] = h;
  ((ushort4*)(wpl + PLW))[i] = l;
}

// ------------------------------------------------------------------
// K1: S = x @ W^T, split-bf16 (3 products), 256x256 tile, BK=32.
// Shell = round-8 best (ring-2, one vmcnt(0)+barrier per K-tile, XCD
// swizzle, stage geometry). Fragments = round-7 proven conflict-free
// map: 16x16x32 MFMA, row = ...+l15, chunk = (4*pl+lq)^(row&7) --
// every HW lane-quad (l,l+16,l+32,l+48) hits 4 distinct 16B columns.
// Slot: [256 rows][128 B] = 2 planes x 4 k-octets; phys = c^(row&7).
// ------------------------------------------------------------------
__device__ __forceinline__ void stageOp(const ushort_t* __restrict__ pl0,
                                        long planeStride, long row0, int t,
                                        int tid, ushort_t* dst /*slot base*/) {
#pragma unroll
  for (int i = 0; i < 4; ++i) {
    int id = i * 512 + tid;          // 0..2047 16B-positions
    int row = id >> 3;               // 0..255
    int ps = id & 7;                 // physical chunk
    int ls = ps ^ (row & 7);         // logical chunk (involution)
    int pl = ls >> 2, ko = ls & 3;
    long goff = (long)pl * planeStride + (row0 + row) * FEA + t * 32 + ko * 8;
    gload_lds16(pl0 + goff, dst + (size_t)id * 8);
  }
}

__global__ __launch_bounds__(512, 2) void gemm_mfma7(
    const ushort_t* __restrict__ xpl, const ushort_t* __restrict__ wpl,
    float* __restrict__ S) {
  __shared__ alignas(16) ushort_t lds[65536];  // A ring2 64 KB | B ring2 64 KB
  ushort_t* ldsA = lds;
  ushort_t* ldsB = lds + 32768;

  const int tid = threadIdx.x;
  const int wid = tid >> 6, lane = tid & 63;
  const int l15 = lane & 15, lq = lane >> 4;   // 16x16 lane map
  const int wm = wid >> 2, wn = wid & 3;       // 2M x 4N waves

  // XCD-chunked bijective swizzle (2048 wgs): proven 197 MB fetch
  int wg = blockIdx.x;
  int xcd = wg & 7, idx = wg >> 3;
  const int mt = xcd * 32 + (idx >> 3);
  const int nt = idx & 7;
  const long rm0 = (long)mt * 256;
  const long cn0 = (long)nt * 256;

  f32x4 acc[8][4] = {};

  // prologue: stage K-tile 0 into slot 0
  stageOp(xpl, PLX, rm0, 0, tid, ldsA);
  stageOp(wpl, PLW, cn0, 0, tid, ldsB);
  asm volatile("s_waitcnt vmcnt(0)" ::: "memory");
  asm volatile("s_barrier" ::: "memory");

  for (int t = 0; t < 16; ++t) {
    const ushort_t* Ab = ldsA + (size_t)(t & 1) * 16384;
    const ushort_t* Bb = ldsB + (size_t)(t & 1) * 16384;

    if (t < 15) {  // stage next tile into the other slot (disjoint, no WAR)
      stageOp(xpl, PLX, rm0, t + 1, tid, ldsA + (size_t)((t + 1) & 1) * 16384);
      stageOp(wpl, PLW, cn0, t + 1, tid, ldsB + (size_t)((t + 1) & 1) * 16384);
    }

    // B fragments (held through the tile): 4 nf x 2 planes
    bf16x8 b[4][2];
#pragma unroll
    for (int nf = 0; nf < 4; ++nf) {
      int r = wn * 64 + nf * 16 + l15;
      int rx = r & 7;
#pragma unroll
      for (int pl = 0; pl < 2; ++pl)
        b[nf][pl] = *(const bf16x8*)(Bb + r * 64 + ((((pl << 2) + lq) ^ rx) * 8));
    }

    // two half-passes over mf to bound live A regs
#pragma unroll
    for (int h = 0; h < 2; ++h) {
      bf16x8 a[4][2];
#pragma unroll
      for (int mi = 0; mi < 4; ++mi) {
        int r = wm * 128 + (h * 4 + mi) * 16 + l15;
        int rx = r & 7;
#pragma unroll
        for (int pl = 0; pl < 2; ++pl)
          a[mi][pl] = *(const bf16x8*)(Ab + r * 64 + ((((pl << 2) + lq) ^ rx) * 8));
      }
      __builtin_amdgcn_s_setprio(1);
      // product-major: 16 independent MFMAs between acc reuses
#pragma unroll
      for (int mi = 0; mi < 4; ++mi)
#pragma unroll
        for (int nf = 0; nf < 4; ++nf)
          acc[h * 4 + mi][nf] = __builtin_amdgcn_mfma_f32_16x16x32_bf16(
              a[mi][0], b[nf][0], acc[h * 4 + mi][nf], 0, 0, 0);
#pragma unroll
      for (int mi = 0; mi < 4; ++mi)
#pragma unroll
        for (int nf = 0; nf < 4; ++nf)
          acc[h * 4 + mi][nf] = __builtin_amdgcn_mfma_f32_16x16x32_bf16(
              a[mi][0], b[nf][1], acc[h * 4 + mi][nf], 0, 0, 0);
#pragma unroll
      for (int mi = 0; mi < 4; ++mi)
#pragma unroll
        for (int nf = 0; nf < 4; ++nf)
          acc[h * 4 + mi][nf] = __builtin_amdgcn_mfma_f32_16x16x32_bf16(
              a[mi][1], b[nf][0], acc[h * 4 + mi][nf], 0, 0, 0);
      __builtin_amdgcn_s_setprio(0);
    }

    if (t < 15) {
      asm volatile("s_waitcnt vmcnt(0)" ::: "memory");
      asm volatile("s_barrier" ::: "memory");
    }
  }

  // epilogue: 16x16 C/D layout col = lane&15, row = (lane>>4)*4 + reg
#pragma unroll
  for (int mf = 0; mf < 8; ++mf)
#pragma unroll
    for (int nf = 0; nf < 4; ++nf) {
      int col = (int)cn0 + wn * 64 + nf * 16 + l15;
      if (col < MEM) {
        long rbase = rm0 + wm * 128 + mf * 16 + lq * 4;
#pragma unroll
        for (int r = 0; r < 4; ++r)
          S[(rbase + r) * MEM + col] = acc[mf][nf][r];
      }
    }
}

// ------------------------------------------------------------------
// Fallback fp32 GEMM (used only if ws too small)
// ------------------------------------------------------------------
#define BKF 32
__global__ __launch_bounds__(256) void gemm_scores(
    const float* __restrict__ x, const float* __restrict__ Wt,
    float* __restrict__ S) {
  __shared__ float xs[BKF][129];
  __shared__ float ws[BKF][129];
  const int tid = threadIdx.x;
  const int rm0 = blockIdx.x * 128;
  const int cn0 = blockIdx.y * 128;
  const int tx = tid & 15, ty = tid >> 4;
  const int sr = tid >> 3, kq = tid & 7;
  float acc[8][8];
#pragma unroll
  for (int i = 0; i < 8; ++i)
#pragma unroll
    for (int j = 0; j < 8; ++j) acc[i][j] = 0.f;
  for (int k0 = 0; k0 < FEA; k0 += BKF) {
#pragma unroll
    for (int b = 0; b < 4; ++b) {
      const int row = sr + 32 * b;
      float4 v = *(const float4*)(x + (size_t)(rm0 + row) * FEA + k0 + kq * 4);
      xs[kq * 4 + 0][row] = v.x; xs[kq * 4 + 1][row] = v.y;
      xs[kq * 4 + 2][row] = v.z; xs[kq * 4 + 3][row] = v.w;
      int wr = cn0 + row; wr = (wr < MEM) ? wr : (MEM - 1);
      float4 u = *(const float4*)(Wt + (size_t)wr * FEA + k0 + kq * 4);
      ws[kq * 4 + 0][row] = u.x; ws[kq * 4 + 1][row] = u.y;
      ws[kq * 4 + 2][row] = u.z; ws[kq * 4 + 3][row] = u.w;
    }
    __syncthreads();
#pragma unroll 8
    for (int k = 0; k < BKF; ++k) {
      float a[8], bb[8];
      float4 t0 = *(const float4*)&xs[k][4 * ty];
      float4 t1 = *(const float4*)&xs[k][64 + 4 * ty];
      a[0] = t0.x; a[1] = t0.y; a[2] = t0.z; a[3] = t0.w;
      a[4] = t1.x; a[5] = t1.y; a[6] = t1.z; a[7] = t1.w;
      float4 u0 = *(const float4*)&ws[k][4 * tx];
      float4 u1 = *(const float4*)&ws[k][64 + 4 * tx];
      bb[0] = u0.x; bb[1] = u0.y; bb[2] = u0.z; bb[3] = u0.w;
      bb[4] = u1.x; bb[5] = u1.y; bb[6] = u1.z; bb[7] = u1.w;
#pragma unroll
      for (int i = 0; i < 8; ++i)
#pragma unroll
        for (int j = 0; j < 8; ++j)
          acc[i][j] = fmaf(a[i], bb[j], acc[i][j]);
    }
    __syncthreads();
  }
#pragma unroll
  for (int i = 0; i < 8; ++i) {
    const int row = rm0 + ((i < 4) ? (4 * ty + i) : (64 + 4 * ty + (i - 4)));
    const int c0 = cn0 + 4 * tx;
    const int c1 = cn0 + 64 + 4 * tx;
    if (c0 < MEM) {
      float4 v; v.x = acc[i][0]; v.y = acc[i][1]; v.z = acc[i][2]; v.w = acc[i][3];
      *(float4*)(S + (size_t)row * MEM + c0) = v;
    }
    if (c1 < MEM) {
      float4 v; v.x = acc[i][4]; v.y = acc[i][5]; v.z = acc[i][6]; v.w = acc[i][7];
      *(float4*)(S + (size_t)row * MEM + c1) = v;
    }
  }
}

// ------------------------------------------------------------------
// K2: softmax -> hard shrink -> renorm -> write att + sparse out
// ------------------------------------------------------------------
__global__ __launch_bounds__(512) void softmax_shrink_out(
    const float* __restrict__ Wt, float* __restrict__ out,
    float* __restrict__ att /* raw scores on entry */) {
  __shared__ float sl[8 * MEM];
  const int tid = threadIdx.x;
  const int r0 = blockIdx.x * 8;
  {
    const float* Sblk = att + (size_t)r0 * MEM;
#pragma unroll
    for (int jj = 0; jj < 8; ++jj) {
      int q = tid + 512 * jj;
      if (q < (8 * MEM) / 4) {
        float4 v = *(const float4*)(Sblk + 4 * q);
        *(float4*)&sl[4 * q] = v;
      }
    }
  }
  __syncthreads();
  const int w = tid >> 6;
  const int l = tid & 63;
  float* row_lds = &sl[w * MEM];
  const int grow = r0 + w;

  float m = -INFINITY;
  for (int j = 0; j < 32; ++j) {
    int c = l + 64 * j;
    if (c < MEM) m = fmaxf(m, row_lds[c]);
  }
#pragma unroll
  for (int off = 32; off; off >>= 1) m = fmaxf(m, __shfl_xor(m, off));

  float s = 0.f;
  for (int j = 0; j < 32; ++j) {
    int c = l + 64 * j;
    if (c < MEM) {
      float e = expf(row_lds[c] - m);
      row_lds[c] = e;
      s += e;
    }
  }
#pragma unroll
  for (int off = 32; off; off >>= 1) s += __shfl_xor(s, off);

  float qs = 0.f;
  for (int j = 0; j < 32; ++j) {
    int c = l + 64 * j;
    if (c < MEM) {
      float p = row_lds[c] / s;
      float d = p - LAMBDA;
      float q = fmaxf(d, 0.f) * p / (fabsf(d) + EPS);
      row_lds[c] = q;
      qs += q;
    }
  }
#pragma unroll
  for (int off = 32; off; off >>= 1) qs += __shfl_xor(qs, off);
  const float denom = fmaxf(qs, EPS);

  float4 oa0 = {0.f, 0.f, 0.f, 0.f};
  float4 oa1 = {0.f, 0.f, 0.f, 0.f};
  for (int j = 0; j < 32; ++j) {
    int c = l + 64 * j;
    float a = 0.f;
    if (c < MEM) {
      a = row_lds[c] / denom;
      att[(size_t)grow * MEM + c] = a;
    }
    unsigned long long msk = __ballot(a > 0.f);
    while (msk) {
      int b = __ffsll(msk) - 1;
      msk &= msk - 1;
      float av = __shfl(a, b);
      int cc = b + 64 * j;
      const float* wp = Wt + (size_t)cc * FEA;
      float4 w0 = *(const float4*)(wp + 4 * l);
      float4 w1 = *(const float4*)(wp + 256 + 4 * l);
      oa0.x = fmaf(av, w0.x, oa0.x); oa0.y = fmaf(av, w0.y, oa0.y);
      oa0.z = fmaf(av, w0.z, oa0.z); oa0.w = fmaf(av, w0.w, oa0.w);
      oa1.x = fmaf(av, w1.x, oa1.x); oa1.y = fmaf(av, w1.y, oa1.y);
      oa1.z = fmaf(av, w1.z, oa1.z); oa1.w = fmaf(av, w1.w, oa1.w);
    }
  }
  float* op = out + (size_t)grow * FEA;
  *(float4*)(op + 4 * l) = oa0;
  *(float4*)(op + 256 + 4 * l) = oa1;
}

// ------------------------------------------------------------------
extern "C" void kernel_launch(void* const* d_in, const int* in_sizes, int n_in,
                              void* d_out, int out_size, void* d_ws, size_t ws_size,
                              hipStream_t stream) {
  (void)in_sizes; (void)n_in; (void)out_size;
  const float* x = (const float*)d_in[0];
  const float* W = (const float*)d_in[1];
  float* out = (float*)d_out;
  float* att = (float*)d_out + (size_t)NROWS * FEA;

  const size_t w_need = (size_t)PLW * 2 * sizeof(ushort_t);  // 4 MB
  if (ws_size >= w_need) {
    ushort_t* xpl = (ushort_t*)d_out;  // out region: exactly fits 2 x-planes
    ushort_t* wpl = (ushort_t*)d_ws;
    split_x<<<2048, 256, 0, stream>>>(x, xpl);
    split_w<<<(int)(PLW / 4 / 256), 256, 0, stream>>>(W, wpl);
    gemm_mfma7<<<2048, 512, 0, stream>>>(xpl, wpl, att);
  } else {
    dim3 g1(NROWS / 128, (MEM + 127) / 128);
    gemm_scores<<<g1, 256, 0, stream>>>(x, W, att);
  }
  softmax_shrink_out<<<NROWS / 8, 512, 0, stream>>>(W, out, att);
}